// Round 3
// baseline (1042.279 us; speedup 1.0000x reference)
//
#include <hip/hip_runtime.h>
#include <hip/hip_bf16.h>

// GraphCNN fused per-graph MFMA kernel — Round 2: 12-wave restructure.
// 768 threads = 12 waves per block, one block per graph. Wave (mt,cg) owns the
// 32x32 C-tile (rows mt*32.., cols cg*32..) in every step -> all 12 C-tiles of
// each [96][128] intermediate are computed concurrently (was: 4 waves x 3 tiles
// serial). Even/odd K-split gives 2 independent MFMA chains per wave.
// LDS 98,816 B -> 1 block/CU -> 12 waves/CU (3/SIMD), occupancy 37.5%.
//
// MFMA layouts (gfx950, learn_hip m74/m101):
//   A: A[m][k], m = lane&31, k = (lane>>5)*8 + j
//   B: B[k][n], n = lane&31, k = (lane>>5)*8 + j
//   C/D: col = lane&31, row = (reg&3) + 8*(reg>>2) + 4*(lane>>5)

#define NN 90
#define HH 128
#define NT 768

typedef _Float16 half8 __attribute__((ext_vector_type(8)));
typedef _Float16 half4 __attribute__((ext_vector_type(4)));
typedef float floatx16 __attribute__((ext_vector_type(16)));

#define SR 136      // row-major (A-layout) stride, f16 elems; 96 rows
#define SR8 17      // SR/8
#define ST 104      // transposed (B-layout) + adj stride, f16 elems
#define ST8 13      // ST/8
#define ST4 26      // ST/4

#define MFMA(a, b, c) __builtin_amdgcn_mfma_f32_32x32x16_f16((a), (b), (c), 0, 0, 0)

// ---------------- weight prep: fp32 -> fp16, transposed ----------------
// ws layout (f16): W0T [128][96] @0 ; Wr1T, W1T, W2T, Wr2T [128][128] after.
__global__ void prep_weights(const float* __restrict__ W0,
                             const float* __restrict__ Wr1,
                             const float* __restrict__ W1,
                             const float* __restrict__ W2,
                             const float* __restrict__ Wr2,
                             _Float16* __restrict__ ws)
{
    const int idx = blockIdx.x * blockDim.x + threadIdx.x;
    if (idx >= 77824) return;
    if (idx < 12288) {                       // W0T[n][k], k padded 90->96 w/ zeros
        const int n = idx / 96, k = idx - n * 96;
        ws[idx] = (k < NN) ? (_Float16)W0[k * HH + n] : (_Float16)0.f;
    } else {
        const int j = idx - 12288;
        const int m = j >> 14;               // which 128x128 matrix
        const int r = j & 16383;
        const int n = r >> 7, k = r & 127;
        const float* src = (m == 0) ? Wr1 : (m == 1) ? W1 : (m == 2) ? W2 : Wr2;
        ws[idx] = (_Float16)src[k * HH + n];
    }
}

// ---------------- main fused kernel ----------------
__global__ __launch_bounds__(NT, 3) void graphcnn_mfma(
    const float* __restrict__ adj,
    const _Float16* __restrict__ wts,
    const float* __restrict__ b0, const float* __restrict__ b1,
    const float* __restrict__ b2, const float* __restrict__ br1,
    const float* __restrict__ br2,
    float* __restrict__ out)
{
    // LDS: adjH [96][104] f16 | bufA [96][136] (h0R->tR->uR) |
    //      bufT [128][104] (h0T->xT) reused as YR [96][136] | r1R [96][136]
    __shared__ __align__(16) unsigned char smem[98816];
    _Float16* adjH = (_Float16*)smem;
    _Float16* bufA = (_Float16*)(smem + 19968);
    _Float16* bufT = (_Float16*)(smem + 46080);
    _Float16* r1R  = (_Float16*)(smem + 72704);

    const int t    = threadIdx.x;
    const int wv   = t >> 6;           // 0..11
    const int lane = t & 63;
    const int p    = lane & 31;
    const int h    = lane >> 5;
    const int mt   = wv >> 2;          // M-tile 0..2 (rows mt*32..mt*32+31)
    const int cg   = wv & 3;           // col-group 0..3
    const int n    = cg * 32 + p;      // owned hidden column
    const int arow = mt * 32 + p;      // owned A-operand row

    const _Float16* W0T  = wts;                 // [128][96]
    const _Float16* Wr1T = wts + 12288;         // [128][128]
    const _Float16* W1T  = Wr1T + 16384;
    const _Float16* W2T  = W1T + 16384;
    const _Float16* Wr2T = W2T + 16384;

    // ---- zero adjH (pads must be finite-zero), then stage adj fp32->fp16 ----
    for (int i = t; i < (96 * ST) / 2; i += NT) ((unsigned int*)adjH)[i] = 0u;
    __syncthreads();
    const float* Ag = adj + (size_t)blockIdx.x * (NN * NN);
    for (int i = t; i < NN * NN; i += NT) {
        const int r = i / NN, c = i - r * NN;
        adjH[r * ST + c] = (_Float16)Ag[i];
    }
    __syncthreads();

    // fragment loaders / writers (single 32x32 tile per wave)
    auto ldA = [&](const _Float16* buf, int s8, int kt) {
        return ((const half8*)buf)[arow * s8 + kt * 2 + h];
    };
    auto writeR = [&](_Float16* buf, const floatx16& A) {
        #pragma unroll
        for (int r = 0; r < 16; r++) {
            const int node = mt * 32 + (r & 3) + 8 * (r >> 2) + 4 * h;
            buf[node * SR + n] = (_Float16)A[r];
        }
    };
    auto writeT = [&](_Float16* buf, const floatx16& A) {
        #pragma unroll
        for (int rg = 0; rg < 4; rg++) {
            half4 v = { (_Float16)A[4*rg], (_Float16)A[4*rg+1],
                        (_Float16)A[4*rg+2], (_Float16)A[4*rg+3] };
            ((half4*)buf)[n * ST4 + mt * 8 + 2 * rg + h] = v;
        }
    };

    floatx16 r1reg;   // r1 C-tile kept in registers for S4's elementwise add

    // ===== S1: h0 = adj @ W0 + b0  -> bufA (R) and bufT (T) =====
    {
        half8 bf[6];
        #pragma unroll
        for (int kt = 0; kt < 6; kt++) bf[kt] = ((const half8*)W0T)[n * 12 + kt * 2 + h];
        const float bias = b0[n];
        floatx16 ae, ao;
        #pragma unroll
        for (int r = 0; r < 16; r++) { ae[r] = bias; ao[r] = 0.f; }
        #pragma unroll
        for (int kt = 0; kt < 6; kt += 2) {
            ae = MFMA(ldA(adjH, ST8, kt),     bf[kt],     ae);
            ao = MFMA(ldA(adjH, ST8, kt + 1), bf[kt + 1], ao);
        }
        floatx16 acc = ae + ao;
        writeR(bufA, acc);
        writeT(bufT, acc);
    }
    __syncthreads();

    // ===== S2: r1 = h0R @ Wr1 + br1 -> regs + r1R =====
    {
        half8 bf[8];
        #pragma unroll
        for (int kt = 0; kt < 8; kt++) bf[kt] = ((const half8*)Wr1T)[n * 16 + kt * 2 + h];
        const float bias = br1[n];
        floatx16 ae, ao;
        #pragma unroll
        for (int r = 0; r < 16; r++) { ae[r] = bias; ao[r] = 0.f; }
        #pragma unroll
        for (int kt = 0; kt < 8; kt += 2) {
            ae = MFMA(ldA(bufA, SR8, kt),     bf[kt],     ae);
            ao = MFMA(ldA(bufA, SR8, kt + 1), bf[kt + 1], ao);
        }
        r1reg = ae + ao;
        writeR(r1R, r1reg);
    }
    __syncthreads();

    // ===== S3: t = adj @ h0 (B from bufT) -> bufA (R) =====
    {
        floatx16 ae, ao;
        #pragma unroll
        for (int r = 0; r < 16; r++) { ae[r] = 0.f; ao[r] = 0.f; }
        #pragma unroll
        for (int kt = 0; kt < 6; kt += 2) {
            half8 b0v = ((const half8*)bufT)[n * ST8 + kt * 2 + h];
            half8 b1v = ((const half8*)bufT)[n * ST8 + (kt + 1) * 2 + h];
            ae = MFMA(ldA(adjH, ST8, kt),     b0v, ae);
            ao = MFMA(ldA(adjH, ST8, kt + 1), b1v, ao);
        }
        floatx16 acc = ae + ao;
        __syncthreads();           // everyone done reading h0R/h0T
        writeR(bufA, acc);
    }
    __syncthreads();

    // ===== S4: x = relu(t @ W1 + b1) + r1reg -> bufT (T) =====
    {
        half8 bf[8];
        #pragma unroll
        for (int kt = 0; kt < 8; kt++) bf[kt] = ((const half8*)W1T)[n * 16 + kt * 2 + h];
        const float bias = b1[n];
        floatx16 ae, ao;
        #pragma unroll
        for (int r = 0; r < 16; r++) { ae[r] = bias; ao[r] = 0.f; }
        #pragma unroll
        for (int kt = 0; kt < 8; kt += 2) {
            ae = MFMA(ldA(bufA, SR8, kt),     bf[kt],     ae);
            ao = MFMA(ldA(bufA, SR8, kt + 1), bf[kt + 1], ao);
        }
        floatx16 xv;
        #pragma unroll
        for (int r = 0; r < 16; r++) xv[r] = fmaxf(ae[r] + ao[r], 0.f) + r1reg[r];
        __syncthreads();           // everyone done reading tR (bufA) & h0T (bufT)
        writeT(bufT, xv);
    }
    __syncthreads();

    // ===== S5: u = adj @ x (B from bufT) -> bufA (R) =====
    {
        floatx16 ae, ao;
        #pragma unroll
        for (int r = 0; r < 16; r++) { ae[r] = 0.f; ao[r] = 0.f; }
        #pragma unroll
        for (int kt = 0; kt < 6; kt += 2) {
            half8 b0v = ((const half8*)bufT)[n * ST8 + kt * 2 + h];
            half8 b1v = ((const half8*)bufT)[n * ST8 + (kt + 1) * 2 + h];
            ae = MFMA(ldA(adjH, ST8, kt),     b0v, ae);
            ao = MFMA(ldA(adjH, ST8, kt + 1), b1v, ao);
        }
        floatx16 acc = ae + ao;
        __syncthreads();           // everyone done reading tR
        writeR(bufA, acc);
    }
    __syncthreads();

    // ===== S6: Y = relu(u@W2 + r1@Wr2 + b2 + br2) -> YR (bufT region, R) =====
    {
        half8 bf[8], bg[8];
        #pragma unroll
        for (int kt = 0; kt < 8; kt++) {
            bf[kt] = ((const half8*)W2T)[n * 16 + kt * 2 + h];
            bg[kt] = ((const half8*)Wr2T)[n * 16 + kt * 2 + h];
        }
        const float bias = b2[n] + br2[n];
        floatx16 au, ar;
        #pragma unroll
        for (int r = 0; r < 16; r++) { au[r] = bias; ar[r] = 0.f; }
        #pragma unroll
        for (int kt = 0; kt < 8; kt++) {
            au = MFMA(ldA(bufA, SR8, kt), bf[kt], au);   // u @ W2
            ar = MFMA(ldA(r1R,  SR8, kt), bg[kt], ar);   // r1 @ Wr2
        }
        floatx16 yv;
        #pragma unroll
        for (int r = 0; r < 16; r++) yv[r] = fmaxf(au[r] + ar[r], 0.f);
        __syncthreads();           // everyone done reading xT (bufT)
        writeR(bufT, yv);          // YR, stride SR, fits in bufT region
    }
    __syncthreads();

    // ===== S7: Z = Y @ Y^T -> out; 9 ztiles on waves 0-8 =====
    if (wv < 9) {
        const _Float16* YR = bufT;
        const int zm = wv / 3, zn = wv - zm * 3;
        float* outb = out + (size_t)blockIdx.x * (NN * NN);
        floatx16 ze, zo;
        #pragma unroll
        for (int r = 0; r < 16; r++) { ze[r] = 0.f; zo[r] = 0.f; }
        #pragma unroll
        for (int kt = 0; kt < 8; kt += 2) {
            half8 av0 = ((const half8*)YR)[(zm * 32 + p) * SR8 + kt * 2 + h];
            half8 bv0 = ((const half8*)YR)[(zn * 32 + p) * SR8 + kt * 2 + h];
            half8 av1 = ((const half8*)YR)[(zm * 32 + p) * SR8 + (kt + 1) * 2 + h];
            half8 bv1 = ((const half8*)YR)[(zn * 32 + p) * SR8 + (kt + 1) * 2 + h];
            ze = MFMA(av0, bv0, ze);
            zo = MFMA(av1, bv1, zo);
        }
        const int col = zn * 32 + p;
        if (col < NN) {
            #pragma unroll
            for (int r = 0; r < 16; r++) {
                const int row = zm * 32 + (r & 3) + 8 * (r >> 2) + 4 * h;
                if (row < NN) outb[row * NN + col] = ze[r] + zo[r];
            }
        }
    }
}

extern "C" void kernel_launch(void* const* d_in, const int* in_sizes, int n_in,
                              void* d_out, int out_size, void* d_ws, size_t ws_size,
                              hipStream_t stream) {
    const float* adj = (const float*)d_in[0];
    const float* W0  = (const float*)d_in[1];
    const float* b0  = (const float*)d_in[2];
    const float* W1  = (const float*)d_in[3];
    const float* b1  = (const float*)d_in[4];
    const float* W2  = (const float*)d_in[5];
    const float* b2  = (const float*)d_in[6];
    const float* Wr1 = (const float*)d_in[7];
    const float* br1 = (const float*)d_in[8];
    const float* Wr2 = (const float*)d_in[9];
    const float* br2 = (const float*)d_in[10];
    float* out = (float*)d_out;
    _Float16* wts = (_Float16*)d_ws;

    prep_weights<<<76, 1024, 0, stream>>>(W0, Wr1, W1, W2, Wr2, wts);

    const int B = in_sizes[0] / (NN * NN);
    graphcnn_mfma<<<B, NT, 0, stream>>>(adj, wts, b0, b1, b2, br1, br2, out);
}